// Round 13
// baseline (262.821 us; speedup 1.0000x reference)
//
#include <hip/hip_runtime.h>

#define N_E   1024
#define EDIM  256
#define BB    16
#define TT    1024
#define NROW  (BB*TT)        /* 16384 */
#define NCOL  1025
#define NPAD  1152           /* row-major e row stride */
#define PERS  (0.1f/1024.0f)
#define EPSC  (1e-6f/1024.0f)

/* d_out layout (float32): z_q [0,4194304) | loss 4194304 | ind [4194305,+16384) | v 4210689 */
#define OUT_LOSS 4194304
#define OUT_IDX  4194305
#define OUT_V    4210689

/* ws layout (bytes) */
#define WS_ZB   0ull                               /* 16384*256*2  = 8388608  */
#define WS_BBF  8388608ull                         /* 1152*256*2   = 589824   */
#define WS_BSQ  8978432ull                         /* 1152*4       = 4608     */
#define WS_E    8983552ull                         /* 16384*1152*4 = 75497472 */
#define WS_IND  84481024ull                        /* 16384*4                 */
#define WS_PART 84546560ull                        /* 128*4                   */

typedef __attribute__((ext_vector_type(8))) short short8;
typedef __attribute__((ext_vector_type(4))) float floatx4;

__device__ __forceinline__ unsigned short f2bf(float f) {
    unsigned int u = __float_as_uint(f);
    u = (u + 0x7fffu + ((u >> 16) & 1u)) >> 16;   /* RNE */
    return (unsigned short)u;
}

__device__ __forceinline__ float gload_f32(const float* p) {
    float r;
    asm volatile("global_load_dword %0, %1, off" : "=v"(r) : "v"(p));
    return r;
}

/* ---------------- K0: convert z/book -> bf16, compute bsq (fp32) ---------------- */
__global__ __launch_bounds__(256) void k0_prep(const float* __restrict__ z,
                                               const float* __restrict__ book,
                                               unsigned short* __restrict__ zb,
                                               unsigned short* __restrict__ bb,
                                               float* __restrict__ bsq) {
    int bx = blockIdx.x, tid = threadIdx.x;
    if (bx < 4096) {                     /* z: 4096 blocks * 256 thr * 4 floats */
        float4 v = ((const float4*)z)[bx * 256 + tid];
        size_t o = ((size_t)bx * 256 + tid) * 4;
        zb[o + 0] = f2bf(v.x); zb[o + 1] = f2bf(v.y);
        zb[o + 2] = f2bf(v.z); zb[o + 3] = f2bf(v.w);
    } else {                             /* book rows, padded to 1152 with zeros */
        int row = bx - 4096;             /* 0..1151 */
        float v = (row < NCOL) ? book[(size_t)row * EDIM + tid] : 0.0f;
        bb[(size_t)row * EDIM + tid] = f2bf(v);
        __shared__ float sd[256];
        sd[tid] = v * v;
        __syncthreads();
        for (int s = 128; s > 0; s >>= 1) { if (tid < s) sd[tid] += sd[tid + s]; __syncthreads(); }
        if (tid == 0) bsq[row] = sd[0];
    }
}

/* ---------------- K1: e[r][n] = bsq[n] - 2 * dot(z[r], book[n])  (bf16 MFMA) ---- */
__global__ __launch_bounds__(256) void k1_gemm(const unsigned short* __restrict__ zb,
                                               const unsigned short* __restrict__ bb,
                                               const float* __restrict__ bsq,
                                               float* __restrict__ e) {
    int tid = threadIdx.x;
    int lane = tid & 63, w = tid >> 6;
    int mBase = blockIdx.x * 128 + (w >> 1) * 64;
    int nBase = blockIdx.y * 128 + (w & 1) * 64;
    int r = lane & 15, q = lane >> 4;

    floatx4 acc[4][4];
    #pragma unroll
    for (int i = 0; i < 4; i++)
        #pragma unroll
        for (int j = 0; j < 4; j++) acc[i][j] = (floatx4){0.f, 0.f, 0.f, 0.f};

    const short8* A = (const short8*)zb;   /* row stride 256 bf16 = 32 short8 */
    const short8* Bm = (const short8*)bb;

    #pragma unroll
    for (int ks = 0; ks < 8; ks++) {
        int k8 = ks * 4 + q;
        short8 a[4], b[4];
        #pragma unroll
        for (int i = 0; i < 4; i++) a[i] = A[(size_t)(mBase + i * 16 + r) * 32 + k8];
        #pragma unroll
        for (int j = 0; j < 4; j++) b[j] = Bm[(size_t)(nBase + j * 16 + r) * 32 + k8];
        #pragma unroll
        for (int i = 0; i < 4; i++)
            #pragma unroll
            for (int j = 0; j < 4; j++)
                acc[i][j] = __builtin_amdgcn_mfma_f32_16x16x32_bf16(a[i], b[j], acc[i][j], 0, 0, 0);
    }

    float bsql[4];
    #pragma unroll
    for (int j = 0; j < 4; j++) bsql[j] = bsq[nBase + j * 16 + r];

    #pragma unroll
    for (int i = 0; i < 4; i++)
        #pragma unroll
        for (int rr = 0; rr < 4; rr++) {
            int m = mBase + i * 16 + q * 4 + rr;
            float* erow = e + (size_t)m * NPAD;
            #pragma unroll
            for (int j = 0; j < 4; j++)
                erow[nBase + j * 16 + r] = fmaf(-2.0f, acc[i][j][rr], bsql[j]);
        }
}

/* ---------------- K2: serial neighbor scan (r6 structure, 84.7us measured) ----- */
#define DECLW float A0_0, A0_1, A0_2, A0_3, A0_4, A1_0, A1_1, A1_2, A1_3, A1_4; \
              int q_0, q_1, q_2, q_3, q_4;

#define LDOP(S,k) { int _t = _tb + 2*k + _g; _t = _t < 1024 ? _t : 1023; \
                    A##S##_##k = gload_f32(_pe + (size_t)_t * NPAD); }
#define LDSET(S) LDOP(S,0) LDOP(S,1) LDOP(S,2) LDOP(S,3) LDOP(S,4)

#define QCOP(S,k) { float _bv = __shfl_down(A##S##_##k, 1, 32); \
                    int _qv = (int)((_bv - A##S##_##k) * QS); \
                    q_##k = _capn ? 0 : _qv; }
#define QCSET(S) QCOP(S,0) QCOP(S,1) QCOP(S,2) QCOP(S,3) QCOP(S,4)

#define CHS(j,k,h) { int _rel = ind - cbc; \
                     int _qv = __builtin_amdgcn_readlane(q_##k, _rel + h); \
                     bool _stay = (kk <= _qv); \
                     int _ip1 = ind + 1; _ip1 = _ip1 < 1023 ? _ip1 : 1023; \
                     ind = _stay ? ind : _ip1; \
                     kk  = _stay ? kk + 1 : 0; \
                     packed = (lane == j) ? ind : packed; }
#define CHAIN CHS(0,0,0) CHS(1,0,32) CHS(2,1,0) CHS(3,1,32) CHS(4,2,0) \
              CHS(5,2,32) CHS(6,3,0) CHS(7,3,32) CHS(8,4,0) CHS(9,4,32)

#define ITERX(SI, SQ) { \
    int cbI = ind < 992 ? ind : 992;                 /* base, chunk c+2 */ \
    { const float* _pe = eb + cbI + _cl; int _tb = t + 20; LDSET(SI) } \
    __builtin_amdgcn_sched_barrier(0); \
    int packed = 0; \
    CHAIN \
    if (lane < 10 && t + lane < 1024) wind[ibase + t + lane] = packed; \
    __builtin_amdgcn_sched_barrier(0); \
    asm volatile("s_waitcnt vmcnt(6)" ::: "memory"); /* chunk c+1 loads done */ \
    __builtin_amdgcn_sched_barrier(0); \
    { bool _capn = (cbn + _cl == 1023); QCSET(SQ) } \
    cbc = cbn; cbn = cbI; \
    t += 10; }

__global__ __launch_bounds__(256, 1) void k2_scan(const float* __restrict__ z,
                                                  const float* __restrict__ book,
                                                  const float* __restrict__ bsq,
                                                  const float* __restrict__ e,
                                                  int* __restrict__ wind) {
    __shared__ float sb[4]; __shared__ int si[4];

    int b = blockIdx.x, tid = threadIdx.x;
    int lane = tid & 63, w = tid >> 6;

    const float4* zr = (const float4*)(z + (size_t)b * TT * EDIM);  /* t=0 row */
    float4 zv = zr[lane];
    float s = zv.x * zv.x + zv.y * zv.y + zv.z * zv.z + zv.w * zv.w;
    #pragma unroll
    for (int off = 32; off; off >>= 1) s += __shfl_xor(s, off, 64);
    float zsq = s;

    float best = 3.4e38f; int bidx = 0;
    for (int wi = w; wi < 17; wi += 4) {
        int n = wi * 64 + lane;
        if (n < NCOL) {
            const float4* br = (const float4*)(book + (size_t)n * EDIM);
            float c0 = 0.f, c1 = 0.f, c2 = 0.f, c3 = 0.f;
            #pragma unroll 8
            for (int k = 0; k < 64; k++) {
                float4 bo = br[k]; float4 za = zr[k];
                c0 = fmaf(za.x, bo.x, c0); c1 = fmaf(za.y, bo.y, c1);
                c2 = fmaf(za.z, bo.z, c2); c3 = fmaf(za.w, bo.w, c3);
            }
            float cr = (c0 + c1) + (c2 + c3);
            float d0 = (zsq + bsq[n]) - 2.0f * cr;     /* reference-style formation */
            if (d0 < best || (d0 == best && n < bidx)) { best = d0; bidx = n; }
        }
    }
    #pragma unroll
    for (int off = 32; off; off >>= 1) {
        float ob = __shfl_xor(best, off, 64);
        int   oi = __shfl_xor(bidx, off, 64);
        if (ob < best || (ob == best && oi < bidx)) { best = ob; bidx = oi; }
    }
    if (lane == 0) { sb[w] = best; si[w] = bidx; }
    __syncthreads();
    if (w != 0) return;

    best = sb[0]; bidx = si[0];
    for (int i = 1; i < 4; i++) {
        float vv = sb[i]; int ii = si[i];
        if (vv < best || (vv == best && ii < bidx)) { best = vv; bidx = ii; }
    }

    int ind = min(bidx, N_E - 1);
    int kk = 0;                              /* coe = kk * PERS */
    size_t ibase = (size_t)b * TT;
    if (lane == 0) wind[ibase] = ind;

    const float* eb = e + (size_t)b * TT * NPAD;
    const float QS = 1.0f / PERS;            /* 10240 */

    int _g = lane >> 5;                      /* row-in-pair */
    int _cl = lane & 31;                     /* col-in-window */

    DECLW                                    /* A{0,1}_{0..4}, q_{0..4} */

    int cbc = ind < 992 ? ind : 992;         /* base, chunk 0 */
    int cbn = cbc;                           /* base, chunk 1 (drift<=19 ok) */
    { const float* _pe = eb + cbc + _cl; int _tb = 1;  LDSET(0) }
    { const float* _pe = eb + cbn + _cl; int _tb = 11; LDSET(1) }
    asm volatile("s_waitcnt vmcnt(5)" ::: "memory");   /* chunk 0 (+init store) done */
    __builtin_amdgcn_sched_barrier(0);
    { bool _capn = (cbc + _cl == 1023); QCSET(0) }     /* q for chunk 0 */

    int t = 1;
    #pragma unroll 1
    for (int cc = 0; cc < 52; cc++) {        /* 104 chunks of 10 rows (t>=1024 guarded) */
        ITERX(0, 1)
        ITERX(1, 0)
    }
}

/* ---------------- K3f: FUSED loss via e-recompute (no e read!) ------------------
   r12 post-mortem: ~160us hides in k0/k1/k3; k3's 67MB HBM e-read is
   removable because e = f(zb, bb, bsq) and zb/bb are L2/L3-hot (9MB).
   One block per 128 consecutive rows (same batch; ind monotone in t!):
   - sweep A: the <=2 column-chunks spanning [sind[0], sind[127]] are
     MFMA'd; the lane holding (row, col==sind[row]) writes seind[row].
     Same fmaf(-2,acc,bsql) as k1 -> eind BIT-IDENTICAL to e[r][ind].
   - sweep B: all 9 chunks re-MFMA'd; hinge seind[row]-val+EPSC accumulated
     (cols <= 1024 only). Same values as old k3 reading e; only the
     summation order differs (fp reassociation << threshold).
   - z_q gather + idx emit folded in. part[] shrinks to 128 entries.        */
__global__ __launch_bounds__(256) void k3_fused(const unsigned short* __restrict__ zb,
                                                const unsigned short* __restrict__ bb,
                                                const float* __restrict__ bsq,
                                                const int* __restrict__ wind,
                                                const float* __restrict__ book,
                                                float* __restrict__ part,
                                                float* __restrict__ out) {
    int tid = threadIdx.x;
    int lane = tid & 63, w = tid >> 6;
    int r = lane & 15, q = lane >> 4;
    int mB = blockIdx.x * 128;
    int mBase = mB + (w >> 1) * 64;
    int rowW = (w >> 1) * 64;                /* wave's local row base */

    __shared__ int   sind[128];
    __shared__ float seind[128];
    __shared__ float sd[256];

    if (tid < 128) sind[tid] = wind[mB + tid];
    __syncthreads();

    int ca = sind[0] >> 7, cb2 = sind[127] >> 7;   /* monotone ind => cb2 <= ca+1 */

    const short8* A = (const short8*)zb;
    const short8* Bm = (const short8*)bb;

    /* ---- sweep A: extract eind ---- */
    for (int ch = ca; ch <= cb2; ch++) {
        int nBase = ch * 128 + (w & 1) * 64;
        floatx4 acc[4][4];
        #pragma unroll
        for (int i = 0; i < 4; i++)
            #pragma unroll
            for (int j = 0; j < 4; j++) acc[i][j] = (floatx4){0.f, 0.f, 0.f, 0.f};
        #pragma unroll
        for (int ks = 0; ks < 8; ks++) {
            int k8 = ks * 4 + q;
            short8 a[4], b[4];
            #pragma unroll
            for (int i = 0; i < 4; i++) a[i] = A[(size_t)(mBase + i * 16 + r) * 32 + k8];
            #pragma unroll
            for (int j = 0; j < 4; j++) b[j] = Bm[(size_t)(nBase + j * 16 + r) * 32 + k8];
            #pragma unroll
            for (int i = 0; i < 4; i++)
                #pragma unroll
                for (int j = 0; j < 4; j++)
                    acc[i][j] = __builtin_amdgcn_mfma_f32_16x16x32_bf16(a[i], b[j], acc[i][j], 0, 0, 0);
        }
        float bsql[4];
        #pragma unroll
        for (int j = 0; j < 4; j++) bsql[j] = bsq[nBase + j * 16 + r];
        #pragma unroll
        for (int i = 0; i < 4; i++)
            #pragma unroll
            for (int rr = 0; rr < 4; rr++) {
                int rowl = rowW + i * 16 + q * 4 + rr;
                int indr = sind[rowl];
                #pragma unroll
                for (int j = 0; j < 4; j++) {
                    int col = nBase + j * 16 + r;
                    if (col == indr) seind[rowl] = fmaf(-2.0f, acc[i][j][rr], bsql[j]);
                }
            }
    }
    __syncthreads();

    /* ---- sweep B: hinge over all 9 chunks ---- */
    float psum = 0.0f;
    for (int ch = 0; ch < 9; ch++) {
        int nBase = ch * 128 + (w & 1) * 64;
        floatx4 acc[4][4];
        #pragma unroll
        for (int i = 0; i < 4; i++)
            #pragma unroll
            for (int j = 0; j < 4; j++) acc[i][j] = (floatx4){0.f, 0.f, 0.f, 0.f};
        #pragma unroll
        for (int ks = 0; ks < 8; ks++) {
            int k8 = ks * 4 + q;
            short8 a[4], b[4];
            #pragma unroll
            for (int i = 0; i < 4; i++) a[i] = A[(size_t)(mBase + i * 16 + r) * 32 + k8];
            #pragma unroll
            for (int j = 0; j < 4; j++) b[j] = Bm[(size_t)(nBase + j * 16 + r) * 32 + k8];
            #pragma unroll
            for (int i = 0; i < 4; i++)
                #pragma unroll
                for (int j = 0; j < 4; j++)
                    acc[i][j] = __builtin_amdgcn_mfma_f32_16x16x32_bf16(a[i], b[j], acc[i][j], 0, 0, 0);
        }
        float bsql[4];
        #pragma unroll
        for (int j = 0; j < 4; j++) bsql[j] = bsq[nBase + j * 16 + r];
        #pragma unroll
        for (int i = 0; i < 4; i++)
            #pragma unroll
            for (int rr = 0; rr < 4; rr++) {
                int rowl = rowW + i * 16 + q * 4 + rr;
                float ei = seind[rowl];
                #pragma unroll
                for (int j = 0; j < 4; j++) {
                    int col = nBase + j * 16 + r;
                    if (col <= 1024) {
                        float v = ei - fmaf(-2.0f, acc[i][j][rr], bsql[j]) + EPSC;
                        psum += v > 0.0f ? v : 0.0f;
                    }
                }
            }
    }
    sd[tid] = psum; __syncthreads();
    for (int s = 128; s > 0; s >>= 1) { if (tid < s) sd[tid] += sd[tid + s]; __syncthreads(); }
    if (tid == 0) part[blockIdx.x] = sd[0];

    /* ---- z_q gather + idx emit ---- */
    if (tid < 128) out[OUT_IDX + mB + tid] = (float)sind[tid];
    #pragma unroll 4
    for (int rr = 0; rr < 128; rr++) {
        int ind = sind[rr];
        out[(size_t)(mB + rr) * 256 + tid] = book[(size_t)ind * EDIM + tid];
    }
}

/* ---------------- K4: final loss reduce + v ---------------- */
__global__ __launch_bounds__(256) void k4_final(const float* __restrict__ part,
                                                const int* __restrict__ wind,
                                                float* __restrict__ out) {
    int tid = threadIdx.x;
    float s = (tid < 128) ? part[tid] : 0.0f;
    __shared__ float sd[256];
    sd[tid] = s; __syncthreads();
    for (int st = 128; st > 0; st >>= 1) { if (tid < st) sd[tid] += sd[tid + st]; __syncthreads(); }
    if (tid == 0) {
        int mn = wind[0], mx = wind[TT - 1];
        for (int b = 1; b < BB; b++) {
            mn = min(mn, wind[(size_t)b * TT]);
            mx = max(mx, wind[(size_t)b * TT + TT - 1]);
        }
        out[OUT_LOSS] = 1.25f * sd[0] / ((float)NROW * (float)NCOL);
        out[OUT_V] = (float)(mx - mn);
    }
}

extern "C" void kernel_launch(void* const* d_in, const int* in_sizes, int n_in,
                              void* d_out, int out_size, void* d_ws, size_t ws_size,
                              hipStream_t stream) {
    const float* z    = (const float*)d_in[0];
    const float* book = (const float*)d_in[1];
    char* ws = (char*)d_ws;
    unsigned short* zb = (unsigned short*)(ws + WS_ZB);
    unsigned short* bb = (unsigned short*)(ws + WS_BBF);
    float* bsq  = (float*)(ws + WS_BSQ);
    float* e    = (float*)(ws + WS_E);
    int*   wind = (int*)(ws + WS_IND);
    float* part = (float*)(ws + WS_PART);
    float* out  = (float*)d_out;

    hipLaunchKernelGGL(k0_prep,   dim3(4096 + 1152), dim3(256), 0, stream, z, book, zb, bb, bsq);
    hipLaunchKernelGGL(k1_gemm,   dim3(128, 9),      dim3(256), 0, stream, zb, bb, bsq, e);
    hipLaunchKernelGGL(k2_scan,   dim3(16),          dim3(256), 0, stream, z, book, bsq, e, wind);
    hipLaunchKernelGGL(k3_fused,  dim3(128),         dim3(256), 0, stream, zb, bb, bsq, wind, book, part, out);
    hipLaunchKernelGGL(k4_final,  dim3(1),           dim3(256), 0, stream, part, wind, out);
}

// Round 14
// 243.306 us; speedup vs baseline: 1.0802x; 1.0802x over previous
//
#include <hip/hip_runtime.h>

#define N_E   1024
#define EDIM  256
#define BB    16
#define TT    1024
#define NROW  (BB*TT)        /* 16384 */
#define NCOL  1025
#define NPAD  1152           /* row-major e row stride */
#define PERS  (0.1f/1024.0f)
#define EPSC  (1e-6f/1024.0f)

/* d_out layout (float32): z_q [0,4194304) | loss 4194304 | ind [4194305,+16384) | v 4210689 */
#define OUT_LOSS 4194304
#define OUT_IDX  4194305
#define OUT_V    4210689

/* ws layout (bytes) */
#define WS_ZB   0ull                               /* 16384*256*2  = 8388608  */
#define WS_BBF  8388608ull                         /* 1152*256*2   = 589824   */
#define WS_BSQ  8978432ull                         /* 1152*4       = 4608     */
#define WS_E    8983552ull                         /* 16384*1152*4 = 75497472 */
#define WS_IND  84481024ull                        /* 16384*4                 */
#define WS_PART 84546560ull                        /* 16*4                    */

typedef __attribute__((ext_vector_type(8))) short short8;
typedef __attribute__((ext_vector_type(4))) float floatx4;

__device__ __forceinline__ unsigned short f2bf(float f) {
    unsigned int u = __float_as_uint(f);
    u = (u + 0x7fffu + ((u >> 16) & 1u)) >> 16;   /* RNE */
    return (unsigned short)u;
}

__device__ __forceinline__ float gload_f32(const float* p) {
    float r;
    asm volatile("global_load_dword %0, %1, off" : "=v"(r) : "v"(p));
    return r;
}

/* ---------------- K0: convert z/book -> bf16, compute bsq (fp32) ---------------- */
__global__ __launch_bounds__(256) void k0_prep(const float* __restrict__ z,
                                               const float* __restrict__ book,
                                               unsigned short* __restrict__ zb,
                                               unsigned short* __restrict__ bb,
                                               float* __restrict__ bsq) {
    int bx = blockIdx.x, tid = threadIdx.x;
    if (bx < 4096) {                     /* z: 4096 blocks * 256 thr * 4 floats */
        float4 v = ((const float4*)z)[bx * 256 + tid];
        size_t o = ((size_t)bx * 256 + tid) * 4;
        zb[o + 0] = f2bf(v.x); zb[o + 1] = f2bf(v.y);
        zb[o + 2] = f2bf(v.z); zb[o + 3] = f2bf(v.w);
    } else {                             /* book rows, padded to 1152 with zeros */
        int row = bx - 4096;             /* 0..1151 */
        float v = (row < NCOL) ? book[(size_t)row * EDIM + tid] : 0.0f;
        bb[(size_t)row * EDIM + tid] = f2bf(v);
        __shared__ float sd[256];
        sd[tid] = v * v;
        __syncthreads();
        for (int s = 128; s > 0; s >>= 1) { if (tid < s) sd[tid] += sd[tid + s]; __syncthreads(); }
        if (tid == 0) bsq[row] = sd[0];
    }
}

/* ---------------- K1: e[r][n] = bsq[n] - 2 * dot(z[r], book[n])  (bf16 MFMA) ---- */
__global__ __launch_bounds__(256) void k1_gemm(const unsigned short* __restrict__ zb,
                                               const unsigned short* __restrict__ bb,
                                               const float* __restrict__ bsq,
                                               float* __restrict__ e) {
    int tid = threadIdx.x;
    int lane = tid & 63, w = tid >> 6;
    int mBase = blockIdx.x * 128 + (w >> 1) * 64;
    int nBase = blockIdx.y * 128 + (w & 1) * 64;
    int r = lane & 15, q = lane >> 4;

    floatx4 acc[4][4];
    #pragma unroll
    for (int i = 0; i < 4; i++)
        #pragma unroll
        for (int j = 0; j < 4; j++) acc[i][j] = (floatx4){0.f, 0.f, 0.f, 0.f};

    const short8* A = (const short8*)zb;   /* row stride 256 bf16 = 32 short8 */
    const short8* Bm = (const short8*)bb;

    #pragma unroll
    for (int ks = 0; ks < 8; ks++) {
        int k8 = ks * 4 + q;
        short8 a[4], b[4];
        #pragma unroll
        for (int i = 0; i < 4; i++) a[i] = A[(size_t)(mBase + i * 16 + r) * 32 + k8];
        #pragma unroll
        for (int j = 0; j < 4; j++) b[j] = Bm[(size_t)(nBase + j * 16 + r) * 32 + k8];
        #pragma unroll
        for (int i = 0; i < 4; i++)
            #pragma unroll
            for (int j = 0; j < 4; j++)
                acc[i][j] = __builtin_amdgcn_mfma_f32_16x16x32_bf16(a[i], b[j], acc[i][j], 0, 0, 0);
    }

    float bsql[4];
    #pragma unroll
    for (int j = 0; j < 4; j++) bsql[j] = bsq[nBase + j * 16 + r];

    #pragma unroll
    for (int i = 0; i < 4; i++)
        #pragma unroll
        for (int rr = 0; rr < 4; rr++) {
            int m = mBase + i * 16 + q * 4 + rr;
            float* erow = e + (size_t)m * NPAD;
            #pragma unroll
            for (int j = 0; j < 4; j++)
                erow[nBase + j * 16 + r] = fmaf(-2.0f, acc[i][j][rr], bsql[j]);
        }
}

/* -------- worker row task: hinge partial (per-lane accum) + z_q + idx -------- */
__device__ __forceinline__ float row_work(const float* er, int id, int lane,
                                          const float4* book4, float4* out4,
                                          float* out, size_t grow) {
    float eind = er[id];
    const float4* er4 = (const float4*)er;
    float4 x0 = er4[lane], x1 = er4[lane + 64], x2 = er4[lane + 128], x3 = er4[lane + 192];
    float e1024 = er[1024];
    float p = 0.f;
#define HG(v) { float _h = eind - (v) + EPSC; p += _h > 0.f ? _h : 0.f; }
    HG(x0.x) HG(x0.y) HG(x0.z) HG(x0.w)
    HG(x1.x) HG(x1.y) HG(x1.z) HG(x1.w)
    HG(x2.x) HG(x2.y) HG(x2.z) HG(x2.w)
    HG(x3.x) HG(x3.y) HG(x3.z) HG(x3.w)
    if (lane == 0) { float _h = eind - e1024 + EPSC; p += _h > 0.f ? _h : 0.f; }
#undef HG
    out4[grow * 64 + lane] = book4[(size_t)id * 64 + lane];
    if (lane == 0) out[OUT_IDX + grow] = (float)id;
    return p;
}

/* ---------------- K2: scan + FUSED per-row loss/z_q (1024 threads) -------------
   r13 post-mortem: non-k2 remainder is a stable 156us; k3 is a pure consumer
   of wind and e while k2 leaves 240 CUs and 15/16 waves idle. Fold k3 in:
   wave 0 = r6's proven scanner (verbatim pipeline, +setprio around chain,
   T5's exact regime); waves 1-15 = workers streaming e rows (4x float4 =
   8 lines/instr, the high-MLP shape phase A proved fast), per-lane hinge
   accumulation (ONE reduce per block), z_q float4 copy, idx emit.
   Protocol: full-size sind_lds[1024] + monotone done_cnt (no ring reuse, no
   ABA; r11-proven fence pattern: ds_writes, lgkmcnt(0), volatile flag).
   Worker w handles chunks c == w-1 (mod 15), rows 1+10c..10+10c (t<1024);
   wave 1 additionally does row 0 via ind0 flag. Loss values bit-identical
   to old k3 (same eind, same er[n], same hinge); only summation order
   differs (reassociation, << threshold, passed in r12/r13).                 */

#define DECLW float A0_0, A0_1, A0_2, A0_3, A0_4, A1_0, A1_1, A1_2, A1_3, A1_4; \
              int q_0, q_1, q_2, q_3, q_4;

#define LDOP(S,k) { int _t = _tb + 2*k + _g; _t = _t < 1024 ? _t : 1023; \
                    A##S##_##k = gload_f32(_pe + (size_t)_t * NPAD); }
#define LDSET(S) LDOP(S,0) LDOP(S,1) LDOP(S,2) LDOP(S,3) LDOP(S,4)

#define QCOP(S,k) { float _bv = __shfl_down(A##S##_##k, 1, 32); \
                    int _qv = (int)((_bv - A##S##_##k) * QS); \
                    q_##k = _capn ? 0 : _qv; }
#define QCSET(S) QCOP(S,0) QCOP(S,1) QCOP(S,2) QCOP(S,3) QCOP(S,4)

#define CHS(j,k,h) { int _rel = ind - cbc; \
                     int _qv = __builtin_amdgcn_readlane(q_##k, _rel + h); \
                     bool _stay = (kk <= _qv); \
                     int _ip1 = ind + 1; _ip1 = _ip1 < 1023 ? _ip1 : 1023; \
                     ind = _stay ? ind : _ip1; \
                     kk  = _stay ? kk + 1 : 0; \
                     packed = (lane == j) ? ind : packed; }
#define CHAIN CHS(0,0,0) CHS(1,0,32) CHS(2,1,0) CHS(3,1,32) CHS(4,2,0) \
              CHS(5,2,32) CHS(6,3,0) CHS(7,3,32) CHS(8,4,0) CHS(9,4,32)

#define ITERX(SI, SQ) { \
    int cbI = ind < 992 ? ind : 992;                 /* base, chunk c+2 */ \
    { const float* _pe = eb + cbI + _cl; int _tb = t + 20; LDSET(SI) } \
    __builtin_amdgcn_sched_barrier(0); \
    int packed = 0; \
    __builtin_amdgcn_s_setprio(1); \
    CHAIN \
    __builtin_amdgcn_s_setprio(0); \
    if (lane < 10 && t + lane < 1024) { \
        wind[ibase + t + lane] = packed; \
        sind_lds[t + lane] = packed; \
    } \
    asm volatile("s_waitcnt lgkmcnt(0)" ::: "memory"); \
    if (lane == 0) *(volatile int*)&done_cnt_s = cno + 1; \
    cno++; \
    __builtin_amdgcn_sched_barrier(0); \
    asm volatile("s_waitcnt vmcnt(6)" ::: "memory"); /* chunk c+1 loads done */ \
    __builtin_amdgcn_sched_barrier(0); \
    { bool _capn = (cbn + _cl == 1023); QCSET(SQ) } \
    cbc = cbn; cbn = cbI; \
    t += 10; }

__global__ __launch_bounds__(1024, 1) void k2_scan(const float* __restrict__ z,
                                                   const float* __restrict__ book,
                                                   const float* __restrict__ bsq,
                                                   const float* __restrict__ e,
                                                   int* __restrict__ wind,
                                                   float* __restrict__ part,
                                                   float* __restrict__ out) {
    __shared__ float sb[16]; __shared__ int si[16];
    __shared__ int sind_lds[1024];
    __shared__ int done_cnt_s;
    __shared__ int ind0_s;
    __shared__ float sd[1024];

    int b = blockIdx.x, tid = threadIdx.x;
    int lane = tid & 63, w = tid >> 6;

    if (tid == 0) { done_cnt_s = 0; ind0_s = -1; }

    const float4* zr = (const float4*)(z + (size_t)b * TT * EDIM);  /* t=0 row */
    float4 zv = zr[lane];
    float s = zv.x * zv.x + zv.y * zv.y + zv.z * zv.z + zv.w * zv.w;
    #pragma unroll
    for (int off = 32; off; off >>= 1) s += __shfl_xor(s, off, 64);
    float zsq = s;

    float best = 3.4e38f; int bidx = 0;
    for (int wi = w; wi < 17; wi += 16) {
        int n = wi * 64 + lane;
        if (n < NCOL) {
            const float4* br = (const float4*)(book + (size_t)n * EDIM);
            float c0 = 0.f, c1 = 0.f, c2 = 0.f, c3 = 0.f;
            #pragma unroll 8
            for (int k = 0; k < 64; k++) {
                float4 bo = br[k]; float4 za = zr[k];
                c0 = fmaf(za.x, bo.x, c0); c1 = fmaf(za.y, bo.y, c1);
                c2 = fmaf(za.z, bo.z, c2); c3 = fmaf(za.w, bo.w, c3);
            }
            float cr = (c0 + c1) + (c2 + c3);
            float d0 = (zsq + bsq[n]) - 2.0f * cr;     /* reference-style formation */
            if (d0 < best || (d0 == best && n < bidx)) { best = d0; bidx = n; }
        }
    }
    #pragma unroll
    for (int off = 32; off; off >>= 1) {
        float ob = __shfl_xor(best, off, 64);
        int   oi = __shfl_xor(bidx, off, 64);
        if (ob < best || (ob == best && oi < bidx)) { best = ob; bidx = oi; }
    }
    if (lane == 0) { sb[w] = best; si[w] = bidx; }
    __syncthreads();

    if (w != 0) {
        /* ---------------- WORKERS: waves 1..15 ---------------- */
        const float* ebB = e + (size_t)b * TT * NPAD;
        const float4* book4 = (const float4*)book;
        float4* out4 = (float4*)out;
        float psum = 0.f;
        if (w == 1) {
            while (*(volatile int*)&ind0_s < 0) __builtin_amdgcn_s_sleep(1);
            int id0 = *(volatile int*)&ind0_s;
            psum += row_work(ebB, id0, lane, book4, out4, out, (size_t)b * TT);
        }
        #pragma unroll 1
        for (int c = w - 1; c <= 102; c += 15) {
            while (*(volatile int*)&done_cnt_s < c + 1) __builtin_amdgcn_s_sleep(1);
            int tb0 = 1 + 10 * c;
            #pragma unroll 1
            for (int jj = 0; jj < 10; jj++) {
                int t = tb0 + jj;
                if (t >= 1024) break;
                int id = sind_lds[t];
                psum += row_work(ebB + (size_t)t * NPAD, id, lane, book4, out4, out,
                                 (size_t)b * TT + t);
            }
        }
        sd[tid] = psum;
    } else {
        /* ---------------- SCANNER: wave 0 ---------------- */
        best = sb[0]; bidx = si[0];
        for (int i = 1; i < 16; i++) {
            float vv = sb[i]; int ii = si[i];
            if (vv < best || (vv == best && ii < bidx)) { best = vv; bidx = ii; }
        }

        int ind = min(bidx, N_E - 1);
        int kk = 0;                              /* coe = kk * PERS */
        size_t ibase = (size_t)b * TT;
        if (lane == 0) { wind[ibase] = ind; *(volatile int*)&ind0_s = ind; }

        const float* eb = e + (size_t)b * TT * NPAD;
        const float QS = 1.0f / PERS;            /* 10240 */

        int _g = lane >> 5;                      /* row-in-pair */
        int _cl = lane & 31;                     /* col-in-window */
        int cno = 0;

        DECLW                                    /* A{0,1}_{0..4}, q_{0..4} */

        int cbc = ind < 992 ? ind : 992;         /* base, chunk 0 */
        int cbn = cbc;                           /* base, chunk 1 (drift<=19 ok) */
        { const float* _pe = eb + cbc + _cl; int _tb = 1;  LDSET(0) }
        { const float* _pe = eb + cbn + _cl; int _tb = 11; LDSET(1) }
        asm volatile("s_waitcnt vmcnt(5)" ::: "memory");   /* chunk 0 (+init store) done */
        __builtin_amdgcn_sched_barrier(0);
        { bool _capn = (cbc + _cl == 1023); QCSET(0) }     /* q for chunk 0 */

        int t = 1;
        #pragma unroll 1
        for (int cc = 0; cc < 52; cc++) {        /* 104 chunks of 10 rows (t>=1024 guarded) */
            ITERX(0, 1)
            ITERX(1, 0)
        }
        sd[tid] = 0.f;
    }

    __syncthreads();
    for (int s2 = 512; s2 > 0; s2 >>= 1) {
        if (tid < s2) sd[tid] += sd[tid + s2];
        __syncthreads();
    }
    if (tid == 0) part[b] = sd[0];
}

/* ---------------- K4: final loss reduce + v ---------------- */
__global__ __launch_bounds__(256) void k4_final(const float* __restrict__ part,
                                                const int* __restrict__ wind,
                                                float* __restrict__ out) {
    int tid = threadIdx.x;
    float s = (tid < 16) ? part[tid] : 0.0f;
    __shared__ float sd[256];
    sd[tid] = s; __syncthreads();
    for (int st = 128; st > 0; st >>= 1) { if (tid < st) sd[tid] += sd[tid + st]; __syncthreads(); }
    if (tid == 0) {
        int mn = wind[0], mx = wind[TT - 1];
        for (int b = 1; b < BB; b++) {
            mn = min(mn, wind[(size_t)b * TT]);
            mx = max(mx, wind[(size_t)b * TT + TT - 1]);
        }
        out[OUT_LOSS] = 1.25f * sd[0] / ((float)NROW * (float)NCOL);
        out[OUT_V] = (float)(mx - mn);
    }
}

extern "C" void kernel_launch(void* const* d_in, const int* in_sizes, int n_in,
                              void* d_out, int out_size, void* d_ws, size_t ws_size,
                              hipStream_t stream) {
    const float* z    = (const float*)d_in[0];
    const float* book = (const float*)d_in[1];
    char* ws = (char*)d_ws;
    unsigned short* zb = (unsigned short*)(ws + WS_ZB);
    unsigned short* bb = (unsigned short*)(ws + WS_BBF);
    float* bsq  = (float*)(ws + WS_BSQ);
    float* e    = (float*)(ws + WS_E);
    int*   wind = (int*)(ws + WS_IND);
    float* part = (float*)(ws + WS_PART);
    float* out  = (float*)d_out;

    hipLaunchKernelGGL(k0_prep,  dim3(4096 + 1152), dim3(256),  0, stream, z, book, zb, bb, bsq);
    hipLaunchKernelGGL(k1_gemm,  dim3(128, 9),      dim3(256),  0, stream, zb, bb, bsq, e);
    hipLaunchKernelGGL(k2_scan,  dim3(16),          dim3(1024), 0, stream, z, book, bsq, e, wind, part, out);
    hipLaunchKernelGGL(k4_final, dim3(1),           dim3(256),  0, stream, part, wind, out);
}